// Round 10
// baseline (390.935 us; speedup 1.0000x reference)
//
#include <hip/hip_runtime.h>
#include <stdint.h>

#define S_LEN 256
#define DIM   128
#define EPSL  1e-5f

typedef __bf16 bf16x8 __attribute__((ext_vector_type(8)));
typedef float  f32x4  __attribute__((ext_vector_type(4)));

__device__ __forceinline__ unsigned short f2bf_bits(float f) {
  union { float f; unsigned int u; } v; v.f = f;
  unsigned int r = v.u + 0x7fffu + ((v.u >> 16) & 1u);   // RTNE (init paths)
  return (unsigned short)(r >> 16);
}
__device__ __forceinline__ float bf2f_bits(unsigned short b) {
  union { float f; unsigned int u; } v; v.u = ((unsigned int)b) << 16; return v.f;
}
// Hot-path bf16 round-half-up: 2 VALU ops.
__device__ __forceinline__ unsigned f2bf_rhu(float f) {
  return (__float_as_uint(f) + 0x8000u) >> 16;
}
// Pack two floats -> (bf16 lo, bf16 hi) in one u32: 2 adds + 1 v_perm.
__device__ __forceinline__ unsigned pack_rhu(float lo, float hi) {
  return __builtin_amdgcn_perm(__float_as_uint(hi) + 0x8000u,
                               __float_as_uint(lo) + 0x8000u, 0x07060302u);
}
// tanh(x) = 1 - 2/(e^{2x}+1): ~1e-6 rel err, exact at +-inf.
__device__ __forceinline__ float tanh_fast(float x) {
  float e = __expf(2.f * x);
  return 1.f - 2.f * __builtin_amdgcn_rcpf(e + 1.f);
}

// VALU cross-lane via DPP rotation; 16-lane reduce visible on all lanes.
template<int CTRL>
__device__ __forceinline__ float dpp_rot_add(float v) {
  int r = __builtin_amdgcn_update_dpp(0, __float_as_int(v), CTRL, 0xF, 0xF, true);
  return v + __int_as_float(r);
}
template<int CTRL>
__device__ __forceinline__ float dpp_rot_max(float v) {
  int r = __builtin_amdgcn_update_dpp(0, __float_as_int(v), CTRL, 0xF, 0xF, true);
  return fmaxf(v, __int_as_float(r));
}
__device__ __forceinline__ float dpp_sum16(float v) {
  v = dpp_rot_add<0x124>(v); v = dpp_rot_add<0x128>(v);
  v = dpp_rot_add<0x39>(v);  v = dpp_rot_add<0x4E>(v);
  return v;
}
__device__ __forceinline__ float dpp_max16(float v) {
  v = dpp_rot_max<0x124>(v); v = dpp_rot_max<0x128>(v);
  v = dpp_rot_max<0x39>(v);  v = dpp_rot_max<0x4E>(v);
  return v;
}
template<int CTRL>
__device__ __forceinline__ void red_level7(float& s, float& sq, float* d) {
  s  = dpp_rot_add<CTRL>(s);
  sq = dpp_rot_add<CTRL>(sq);
#pragma unroll
  for (int j = 0; j < 5; j++) d[j] = dpp_rot_add<CTRL>(d[j]);
}
template<int JJ>
__device__ __forceinline__ float bcast16(float v) {
  int r = __builtin_amdgcn_ds_swizzle(__float_as_int(v), (JJ << 5) | 0x10);
  return __int_as_float(r);
}

union Frag8 { unsigned short us[8]; bf16x8 v; int4 i4; };

// R9 structure with BALANCED side roles: every wave does core (4 MFMA, acc
// seeded with e-proj xpacc) + eproj (4 MFMA, off-chain) + LN for 2 rows +
// staging for 2 rows (lanes 0-31: group 0 = row 2w, group 1 = row 2w+1).
// Equalized per-wave serial work minimizes barrier skew (R9's LN waves were
// ~2x the staging waves; all 8 waited on the slowest every step).
__global__ __launch_bounds__(512, 2)
void rnn_fused(const int* __restrict__ x, const float* __restrict__ emb,
               const float* __restrict__ Wih1, const float* __restrict__ bih1,
               const float* __restrict__ Whh1, const float* __restrict__ bhh1,
               const float* __restrict__ g1, const float* __restrict__ be1,
               const float* __restrict__ Wih2, const float* __restrict__ bih2,
               const float* __restrict__ Whh2, const float* __restrict__ bhh2,
               const float* __restrict__ g2, const float* __restrict__ be2,
               float* __restrict__ out)
{
  // h/e element (row m, channel c) at m*128 + ((c>>3) ^ (m&15))*8 + (c&7)
  __shared__ __align__(16) unsigned short h_bf[2][16 * 128];   // 8 KB
  __shared__ __align__(16) unsigned short e_bf[2][16 * 128];   // 8 KB
  __shared__ int x_tile[16 * 256];                             // 16 KB

  const int tid  = threadIdx.x;
  const int wave = tid >> 6;
  const int lane = tid & 63;
  const int r0   = blockIdx.x * 16;
  const int l15  = lane & 15;
  const int q    = lane >> 4;
  const bool side = (lane < 32);         // lanes 0-31 carry LN+staging

  for (int i = tid; i < 16 * 256; i += 512)
    x_tile[i] = x[(size_t)(r0 + (i >> 8)) * S_LEN + (i & 255)];
  for (int i = tid; i < 16 * 128; i += 512) h_bf[1][i] = 0;   // h_{-1} = 0

  const int n1 = wave * 16 + l15;
  const float bias1v = bih1[n1] + bhh1[n1];
  bf16x8 wh[4], wih[4];
#pragma unroll
  for (int kt = 0; kt < 4; kt++) {
    int k0 = kt * 32 + q * 8;
    Frag8 fh, fa;
#pragma unroll
    for (int j = 0; j < 8; j++) {
      fh.us[j] = f2bf_bits(Whh1[n1 * DIM + k0 + j]);   // bf16-only Whh
      fa.us[j] = f2bf_bits(Wih1[n1 * DIM + k0 + j]);
    }
    wh[kt] = fh.v; wih[kt] = fa.v;
  }

  // ---- side-role state (lanes 0-31 of every wave) ----
  // LN: group q(0,1) handles row myrow = 2*wave + q.
  // staging: same lanes, row gm = 2*wave + q, oct = l15.
  const int myrow = 2 * wave + (q & 1);
  const int gdst  = myrow * 128 + ((l15 ^ myrow) & 15) * 8;
  float w2g[5][8], Gs[5], Bs[5], wrow[5];
  float t2_l = 0.f, g2_l = 0.f, be2_l = 0.f, validf = 0.f;
  float h2rep[5], pool_l = 0.f;
  float pf[2][8];

  if (side) {
    int coct = (l15 ^ myrow) & 15;       // storage oct l15 -> channels coct*8..+7
#pragma unroll
    for (int j = 0; j < 8; j++) {
      int c = coct * 8 + j;
      float gc = g1[c];
#pragma unroll
      for (int jj = 0; jj < 5; jj++) w2g[jj][j] = Wih2[jj * DIM + c] * gc;
    }
#pragma unroll
    for (int jj = 0; jj < 5; jj++) { Gs[jj] = 0.f; Bs[jj] = 0.f; }
    for (int c = 0; c < DIM; c++) {      // init-only scalar loop
      float gc = g1[c], bc = be1[c];
#pragma unroll
      for (int jj = 0; jj < 5; jj++) {
        float w = Wih2[jj * DIM + c];
        Gs[jj] += w * gc; Bs[jj] += w * bc;
      }
    }
    validf = (l15 < 5) ? 1.f : 0.f;
    if (l15 < 5) {
      t2_l = bih2[l15] + bhh2[l15];
      g2_l = g2[l15]; be2_l = be2[l15];
#pragma unroll
      for (int jj = 0; jj < 5; jj++) wrow[jj] = Whh2[l15 * 5 + jj];
    } else {
#pragma unroll
      for (int jj = 0; jj < 5; jj++) wrow[jj] = 0.f;
    }
#pragma unroll
    for (int jj = 0; jj < 5; jj++) h2rep[jj] = 0.f;
  }
  __syncthreads();

  if (side) {                            // stage e[0],e[1]; preload pf=e[2],e[3]
    float ta[8], tb[8];
    { int xid = x_tile[myrow * 256 + 0];
      const float* pe = emb + (size_t)xid * DIM + l15 * 8;
#pragma unroll
      for (int j = 0; j < 8; j++) ta[j] = pe[j]; }
    { int xid = x_tile[myrow * 256 + 1];
      const float* pe = emb + (size_t)xid * DIM + l15 * 8;
#pragma unroll
      for (int j = 0; j < 8; j++) tb[j] = pe[j]; }
    { int xid = x_tile[myrow * 256 + 2];
      const float* pe = emb + (size_t)xid * DIM + l15 * 8;
#pragma unroll
      for (int j = 0; j < 8; j++) pf[0][j] = pe[j]; }
    { int xid = x_tile[myrow * 256 + 3];
      const float* pe = emb + (size_t)xid * DIM + l15 * 8;
#pragma unroll
      for (int j = 0; j < 8; j++) pf[1][j] = pe[j]; }
    Frag8 pa, pb;
#pragma unroll
    for (int j = 0; j < 8; j++) { pa.us[j] = f2bf_bits(ta[j]); pb.us[j] = f2bf_bits(tb[j]); }
    *(int4*)&e_bf[0][gdst] = pa.i4;
    *(int4*)&e_bf[1][gdst] = pb.i4;
  }
  __syncthreads();

  // xpacc = e[0]@Wih^T + bias for this wave's n-tile (register handoff)
  f32x4 xpacc = {bias1v, bias1v, bias1v, bias1v};
#pragma unroll
  for (int kt = 0; kt < 4; kt++) {
    int sw = (((kt * 4 + q) ^ l15) & 15) * 8;
    bf16x8 ae = *(const bf16x8*)&e_bf[0][l15 * 128 + sw];
    xpacc = __builtin_amdgcn_mfma_f32_16x16x32_bf16(ae, wih[kt], xpacc, 0, 0, 0);
  }
  asm volatile("s_waitcnt lgkmcnt(0)\n\ts_barrier" ::: "memory");

#pragma unroll 2
  for (int t = 0; t <= S_LEN; t++) {
    // ---- serial core: acc seeded with xpacc, ONE depth-4 chain ----
    f32x4 acc = xpacc;
    if (t < S_LEN) {
      const int rb = (t + 1) & 1;        // h_{t-1}
#pragma unroll
      for (int kt = 0; kt < 4; kt++) {
        int sw = (((kt * 4 + q) ^ l15) & 15) * 8;
        bf16x8 ahf = *(const bf16x8*)&h_bf[rb][l15 * 128 + sw];
        acc = __builtin_amdgcn_mfma_f32_16x16x32_bf16(ahf, wh[kt], acc, 0, 0, 0);
      }
      const int wb = t & 1;
      const int oct = n1 >> 3;
#pragma unroll
      for (int r = 0; r < 4; r++) {      // D-layout: row = q*4 + r, col = l15
        int row = q * 4 + r;
        h_bf[wb][row * 128 + ((oct ^ row) & 15) * 8 + (n1 & 7)] =
            (unsigned short)f2bf_rhu(tanh_fast(acc[r]));
      }
    }

    if (t + 1 < S_LEN) {                 // e_{t+1}@Wih into regs (off-chain)
      f32x4 a = {bias1v, bias1v, bias1v, bias1v};
#pragma unroll
      for (int kt = 0; kt < 4; kt++) {
        int sw = (((kt * 4 + q) ^ l15) & 15) * 8;
        bf16x8 ae = *(const bf16x8*)&e_bf[(t + 1) & 1][l15 * 128 + sw];
        a = __builtin_amdgcn_mfma_f32_16x16x32_bf16(ae, wih[kt], a, 0, 0, 0);
      }
      xpacc = a;
    }

    if (side) {
      // ---- staging: this lane's 2-row share ----
      if (t + 2 < S_LEN) {               // stage e[t+2] (gathered at t-2)
        int4 pk;
        pk.x = pack_rhu(pf[t & 1][0], pf[t & 1][1]);
        pk.y = pack_rhu(pf[t & 1][2], pf[t & 1][3]);
        pk.z = pack_rhu(pf[t & 1][4], pf[t & 1][5]);
        pk.w = pack_rhu(pf[t & 1][6], pf[t & 1][7]);
        *(int4*)&e_bf[t & 1][gdst] = pk;
      }
      if (t + 4 < S_LEN) {               // issue gather e[t+4] (2-step cover)
        int xid = x_tile[myrow * 256 + t + 4];
        const float* pe = emb + (size_t)xid * DIM + l15 * 8;
#pragma unroll
        for (int j = 0; j < 8; j++) pf[t & 1][j] = pe[j];
      }
      // ---- LN/RNN2/pool for row myrow (groups 0,1 only) ----
      if (t >= 1) {
        const int hb = (t - 1) & 1;
        Frag8 hr;
        hr.i4 = *(const int4*)&h_bf[hb][myrow * 128 + l15 * 8];
        float s = 0.f, sq = 0.f, d[5] = {0, 0, 0, 0, 0};
#pragma unroll
        for (int j = 0; j < 8; j++) {
          float v = bf2f_bits(hr.us[j]);
          s += v; sq += v * v;
#pragma unroll
          for (int jj = 0; jj < 5; jj++) d[jj] = fmaf(w2g[jj][j], v, d[jj]);
        }
        red_level7<0x124>(s, sq, d);     // one 4-level DPP butterfly, 7 values
        red_level7<0x128>(s, sq, d);
        red_level7<0x39>(s, sq, d);
        red_level7<0x4E>(s, sq, d);
        float mean = s * (1.f / 128.f);
        float var  = sq * (1.f / 128.f) - mean * mean;
        float rstd = rsqrtf(var + EPSL);
        float p[5];
#pragma unroll
        for (int jj = 0; jj < 5; jj++)   // exact fold of LN1+proj
          p[jj] = rstd * (d[jj] - mean * Gs[jj]) + Bs[jj];
        float psel = (l15 == 0) ? p[0] : (l15 == 1) ? p[1] :
                     (l15 == 2) ? p[2] : (l15 == 3) ? p[3] : p[4];
        float a = psel + t2_l;
#pragma unroll
        for (int jj = 0; jj < 5; jj++) a = fmaf(wrow[jj], h2rep[jj], a);
        float xn = tanh_fast(a);         // one tanh issue for both rows' 5 dims
        float s2 = dpp_sum16(xn * validf) * 0.2f;        // mean over 5
        float dd = xn - s2;
        float v2 = dpp_sum16(dd * dd * validf) * 0.2f;   // var over 5
        float r2 = rsqrtf(v2 + EPSL);
        pool_l += dd * r2 * g2_l + be2_l;  // valid only l15<5
        h2rep[0] = bcast16<0>(xn); h2rep[1] = bcast16<1>(xn);
        h2rep[2] = bcast16<2>(xn); h2rep[3] = bcast16<3>(xn);
        h2rep[4] = bcast16<4>(xn);
      }
    }
    // Raw barrier: drain LDS only; global gather loads stay in flight.
    asm volatile("s_waitcnt lgkmcnt(0)\n\ts_barrier" ::: "memory");
  }

  if (side) {                            // softmax over the 5 pool lanes
    float lg = pool_l * (1.f / 256.f);
    float mx = dpp_max16((l15 < 5) ? lg : -3.0e38f);
    float e  = (l15 < 5) ? __expf(lg - mx) : 0.f;
    float sm = dpp_sum16(e);
    if (l15 < 5) out[(size_t)(r0 + myrow) * 5 + l15] = e / sm;
  }
}

extern "C" void kernel_launch(void* const* d_in, const int* in_sizes, int n_in,
                              void* d_out, int out_size, void* d_ws, size_t ws_size,
                              hipStream_t stream) {
  (void)in_sizes; (void)n_in; (void)d_ws; (void)ws_size; (void)out_size;
  rnn_fused<<<dim3(64), dim3(512), 0, stream>>>(
      (const int*)  d_in[0],  (const float*)d_in[1],  (const float*)d_in[2],
      (const float*)d_in[3],  (const float*)d_in[4],  (const float*)d_in[5],
      (const float*)d_in[6],  (const float*)d_in[7],  (const float*)d_in[8],
      (const float*)d_in[9],  (const float*)d_in[10], (const float*)d_in[11],
      (const float*)d_in[12], (const float*)d_in[13], (float*)d_out);
}

// Round 11
// 275.166 us; speedup vs baseline: 1.4207x; 1.4207x over previous
//
#include <hip/hip_runtime.h>
#include <stdint.h>

#define S_LEN 256
#define DIM   128
#define EPSL  1e-5f

typedef __bf16 bf16x8 __attribute__((ext_vector_type(8)));
typedef float  f32x4  __attribute__((ext_vector_type(4)));

__device__ __forceinline__ unsigned short f2bf_bits(float f) {
  union { float f; unsigned int u; } v; v.f = f;
  unsigned int r = v.u + 0x7fffu + ((v.u >> 16) & 1u);   // RTNE (init paths)
  return (unsigned short)(r >> 16);
}
__device__ __forceinline__ float bf2f_bits(unsigned short b) {
  union { float f; unsigned int u; } v; v.u = ((unsigned int)b) << 16; return v.f;
}
// Hot-path bf16 round-half-up: 2 VALU ops.
__device__ __forceinline__ unsigned f2bf_rhu(float f) {
  return (__float_as_uint(f) + 0x8000u) >> 16;
}
// Pack two floats -> (bf16 lo, bf16 hi) in one u32: 2 adds + 1 v_perm.
__device__ __forceinline__ unsigned pack_rhu(float lo, float hi) {
  return __builtin_amdgcn_perm(__float_as_uint(hi) + 0x8000u,
                               __float_as_uint(lo) + 0x8000u, 0x07060302u);
}
// tanh(x) = 1 - 2/(e^{2x}+1): ~1e-6 rel err, exact at +-inf.
__device__ __forceinline__ float tanh_fast(float x) {
  float e = __expf(2.f * x);
  return 1.f - 2.f * __builtin_amdgcn_rcpf(e + 1.f);
}

// VALU cross-lane via DPP rotation; 16-lane reduce visible on all lanes.
template<int CTRL>
__device__ __forceinline__ float dpp_rot_add(float v) {
  int r = __builtin_amdgcn_update_dpp(0, __float_as_int(v), CTRL, 0xF, 0xF, true);
  return v + __int_as_float(r);
}
template<int CTRL>
__device__ __forceinline__ float dpp_rot_max(float v) {
  int r = __builtin_amdgcn_update_dpp(0, __float_as_int(v), CTRL, 0xF, 0xF, true);
  return fmaxf(v, __int_as_float(r));
}
__device__ __forceinline__ float dpp_sum16(float v) {
  v = dpp_rot_add<0x124>(v); v = dpp_rot_add<0x128>(v);
  v = dpp_rot_add<0x39>(v);  v = dpp_rot_add<0x4E>(v);
  return v;
}
__device__ __forceinline__ float dpp_max16(float v) {
  v = dpp_rot_max<0x124>(v); v = dpp_rot_max<0x128>(v);
  v = dpp_rot_max<0x39>(v);  v = dpp_rot_max<0x4E>(v);
  return v;
}
template<int CTRL>
__device__ __forceinline__ void red_level7(float& s, float& sq, float* d) {
  s  = dpp_rot_add<CTRL>(s);
  sq = dpp_rot_add<CTRL>(sq);
#pragma unroll
  for (int j = 0; j < 5; j++) d[j] = dpp_rot_add<CTRL>(d[j]);
}
template<int JJ>
__device__ __forceinline__ float bcast16(float v) {
  int r = __builtin_amdgcn_ds_swizzle(__float_as_int(v), (JJ << 5) | 0x10);
  return __int_as_float(r);
}

union Frag8 { unsigned short us[8]; bf16x8 v; int4 i4; };

// ===================== Kernel 1: serial recurrence only =====================
// R9 core minus the LN role: 8 homogeneous waves (4 MFMA h@Whh chain seeded
// with e-proj xpacc, 4-tanh epilogue, e@Wih off-chain); waves 4-7 e-staging.
// Each wave also streams its h D-fragment to hout (off-chain global stores,
// never waited: raw barrier drains lgkm only). Layer 2 moved to rnn_tail.
__global__ __launch_bounds__(512, 2)
void rnn_core(const int* __restrict__ x, const float* __restrict__ emb,
              const float* __restrict__ Wih1, const float* __restrict__ bih1,
              const float* __restrict__ Whh1, const float* __restrict__ bhh1,
              unsigned short* __restrict__ hout)
{
  __shared__ __align__(16) unsigned short h_bf[2][16 * 128];   // 8 KB
  __shared__ __align__(16) unsigned short e_bf[2][16 * 128];   // 8 KB
  __shared__ int x_tile[16 * 256];                             // 16 KB

  const int tid  = threadIdx.x;
  const int wave = tid >> 6;
  const int lane = tid & 63;
  const int r0   = blockIdx.x * 16;
  const int l15  = lane & 15;
  const int q    = lane >> 4;

  for (int i = tid; i < 16 * 256; i += 512)
    x_tile[i] = x[(size_t)(r0 + (i >> 8)) * S_LEN + (i & 255)];
  for (int i = tid; i < 16 * 128; i += 512) h_bf[1][i] = 0;   // h_{-1} = 0

  const int n1 = wave * 16 + l15;
  const float bias1v = bih1[n1] + bhh1[n1];
  bf16x8 wh[4], wih[4];
#pragma unroll
  for (int kt = 0; kt < 4; kt++) {
    int k0 = kt * 32 + q * 8;
    Frag8 fh, fa;
#pragma unroll
    for (int j = 0; j < 8; j++) {
      fh.us[j] = f2bf_bits(Whh1[n1 * DIM + k0 + j]);
      fa.us[j] = f2bf_bits(Wih1[n1 * DIM + k0 + j]);
    }
    wh[kt] = fh.v; wih[kt] = fa.v;
  }

  const bool stage_role = (wave >= 4);
  float pf[2][8];
  const int gm   = (wave & 3) * 4 + q;   // staging row (waves 4-7)
  const int goct = l15;
  const int gdst = gm * 128 + ((goct ^ gm) & 15) * 8;
  __syncthreads();

  if (stage_role) {                      // stage e[0],e[1]; preload pf=e[2],e[3]
    float ta[8], tb[8];
    { int xid = x_tile[gm * 256 + 0];
      const float* pe = emb + (size_t)xid * DIM + goct * 8;
#pragma unroll
      for (int j = 0; j < 8; j++) ta[j] = pe[j]; }
    { int xid = x_tile[gm * 256 + 1];
      const float* pe = emb + (size_t)xid * DIM + goct * 8;
#pragma unroll
      for (int j = 0; j < 8; j++) tb[j] = pe[j]; }
    { int xid = x_tile[gm * 256 + 2];
      const float* pe = emb + (size_t)xid * DIM + goct * 8;
#pragma unroll
      for (int j = 0; j < 8; j++) pf[0][j] = pe[j]; }
    { int xid = x_tile[gm * 256 + 3];
      const float* pe = emb + (size_t)xid * DIM + goct * 8;
#pragma unroll
      for (int j = 0; j < 8; j++) pf[1][j] = pe[j]; }
    Frag8 pa, pb;
#pragma unroll
    for (int j = 0; j < 8; j++) { pa.us[j] = f2bf_bits(ta[j]); pb.us[j] = f2bf_bits(tb[j]); }
    *(int4*)&e_bf[0][gdst] = pa.i4;
    *(int4*)&e_bf[1][gdst] = pb.i4;
  }
  __syncthreads();

  // xpacc = e[0]@Wih^T + bias for this wave's n-tile (register handoff)
  f32x4 xpacc = {bias1v, bias1v, bias1v, bias1v};
#pragma unroll
  for (int kt = 0; kt < 4; kt++) {
    int sw = (((kt * 4 + q) ^ l15) & 15) * 8;
    bf16x8 ae = *(const bf16x8*)&e_bf[0][l15 * 128 + sw];
    xpacc = __builtin_amdgcn_mfma_f32_16x16x32_bf16(ae, wih[kt], xpacc, 0, 0, 0);
  }
  asm volatile("s_waitcnt lgkmcnt(0)\n\ts_barrier" ::: "memory");

#pragma unroll 2
  for (int t = 0; t < S_LEN; t++) {
    // ---- serial core: acc seeded with xpacc, ONE depth-4 chain ----
    f32x4 acc = xpacc;
    {
      const int rb = (t + 1) & 1;        // h_{t-1}
#pragma unroll
      for (int kt = 0; kt < 4; kt++) {
        int sw = (((kt * 4 + q) ^ l15) & 15) * 8;
        bf16x8 ahf = *(const bf16x8*)&h_bf[rb][l15 * 128 + sw];
        acc = __builtin_amdgcn_mfma_f32_16x16x32_bf16(ahf, wh[kt], acc, 0, 0, 0);
      }
      const int wb = t & 1;
      const int oct = n1 >> 3;
#pragma unroll
      for (int r = 0; r < 4; r++) {      // D-layout: row = q*4 + r, col = l15
        int row = q * 4 + r;
        unsigned short us = (unsigned short)f2bf_rhu(tanh_fast(acc[r]));
        h_bf[wb][row * 128 + ((oct ^ row) & 15) * 8 + (n1 & 7)] = us;
        // off-chain h stream-out for rnn_tail (never waited in-loop)
        hout[((size_t)(r0 + row) * S_LEN + t) * DIM + n1] = us;
      }
    }

    if (t + 1 < S_LEN) {                 // e_{t+1}@Wih into regs (off-chain)
      f32x4 a = {bias1v, bias1v, bias1v, bias1v};
#pragma unroll
      for (int kt = 0; kt < 4; kt++) {
        int sw = (((kt * 4 + q) ^ l15) & 15) * 8;
        bf16x8 ae = *(const bf16x8*)&e_bf[(t + 1) & 1][l15 * 128 + sw];
        a = __builtin_amdgcn_mfma_f32_16x16x32_bf16(ae, wih[kt], a, 0, 0, 0);
      }
      xpacc = a;
    }

    if (stage_role) {
      if (t + 2 < S_LEN) {               // stage e[t+2] (gathered at t-2)
        int4 pk;
        pk.x = pack_rhu(pf[t & 1][0], pf[t & 1][1]);
        pk.y = pack_rhu(pf[t & 1][2], pf[t & 1][3]);
        pk.z = pack_rhu(pf[t & 1][4], pf[t & 1][5]);
        pk.w = pack_rhu(pf[t & 1][6], pf[t & 1][7]);
        *(int4*)&e_bf[t & 1][gdst] = pk;
      }
      if (t + 4 < S_LEN) {               // issue gather e[t+4] (2-step cover)
        int xid = x_tile[gm * 256 + t + 4];
        const float* pe = emb + (size_t)xid * DIM + goct * 8;
#pragma unroll
        for (int j = 0; j < 8; j++) pf[t & 1][j] = pe[j];
      }
    }
    // Raw barrier: drain LDS only; gathers and h-stores stay in flight.
    asm volatile("s_waitcnt lgkmcnt(0)\n\ts_barrier" ::: "memory");
  }
}

// ===================== Kernel 2: layer-2 tail (parallel) ====================
// 256 blocks x 4 waves; wave owns batch row b. 4-t chunks: LN1+proj parallel
// across the wave's four 16-lane groups, then 4 serial RNN2/LN2/pool steps via
// a per-wave LDS p-handoff. No block barriers. Software-pipelined h loads.
__global__ __launch_bounds__(256, 2)
void rnn_tail(const unsigned short* __restrict__ hall,
              const float* __restrict__ g1,  const float* __restrict__ be1,
              const float* __restrict__ Wih2, const float* __restrict__ bih2,
              const float* __restrict__ Whh2, const float* __restrict__ bhh2,
              const float* __restrict__ g2,  const float* __restrict__ be2,
              float* __restrict__ out)
{
  __shared__ float p_lds[4][4][8];       // [wave][t-sub][5 (pad 8)]
  const int tid  = threadIdx.x;
  const int wave = tid >> 6;
  const int lane = tid & 63;
  const int l15  = lane & 15;
  const int q    = lane >> 4;
  const int b    = blockIdx.x * 4 + wave;

  float w2g[5][8], Gs[5], Bs[5], wrow[5];
#pragma unroll
  for (int j = 0; j < 8; j++) {
    int c = l15 * 8 + j;                 // plain row-major channels now
    float gc = g1[c];
#pragma unroll
    for (int jj = 0; jj < 5; jj++) w2g[jj][j] = Wih2[jj * DIM + c] * gc;
  }
#pragma unroll
  for (int jj = 0; jj < 5; jj++) { Gs[jj] = 0.f; Bs[jj] = 0.f; }
  for (int c = 0; c < DIM; c++) {
    float gc = g1[c], bc = be1[c];
#pragma unroll
    for (int jj = 0; jj < 5; jj++) {
      float w = Wih2[jj * DIM + c];
      Gs[jj] += w * gc; Bs[jj] += w * bc;
    }
  }
  const float validf = (l15 < 5) ? 1.f : 0.f;
  float t2_l = 0.f, g2_l = 0.f, be2_l = 0.f;
  if (l15 < 5) {
    t2_l = bih2[l15] + bhh2[l15];
    g2_l = g2[l15]; be2_l = be2[l15];
#pragma unroll
    for (int jj = 0; jj < 5; jj++) wrow[jj] = Whh2[l15 * 5 + jj];
  } else {
#pragma unroll
    for (int jj = 0; jj < 5; jj++) wrow[jj] = 0.f;
  }
  float h2rep[5];
#pragma unroll
  for (int jj = 0; jj < 5; jj++) h2rep[jj] = 0.f;
  float pool_l = 0.f;

  const unsigned short* hb = hall + (size_t)b * S_LEN * DIM;
  // group q handles t = t0 + q; lane reads 16B of its row chunk
  uint4 hpre = *(const uint4*)(hb + q * DIM + l15 * 8);

  for (int t0 = 0; t0 < S_LEN; t0 += 4) {
    uint4 cur = hpre;
    if (t0 + 4 < S_LEN)                  // prefetch next chunk (off-chain)
      hpre = *(const uint4*)(hb + (size_t)(t0 + 4 + q) * DIM + l15 * 8);
    float hv[8];
    hv[0] = __uint_as_float(cur.x << 16); hv[1] = __uint_as_float(cur.x & 0xffff0000u);
    hv[2] = __uint_as_float(cur.y << 16); hv[3] = __uint_as_float(cur.y & 0xffff0000u);
    hv[4] = __uint_as_float(cur.z << 16); hv[5] = __uint_as_float(cur.z & 0xffff0000u);
    hv[6] = __uint_as_float(cur.w << 16); hv[7] = __uint_as_float(cur.w & 0xffff0000u);
    float s = 0.f, sq = 0.f, d[5] = {0, 0, 0, 0, 0};
#pragma unroll
    for (int j = 0; j < 8; j++) {
      float v = hv[j];
      s += v; sq += v * v;
#pragma unroll
      for (int jj = 0; jj < 5; jj++) d[jj] = fmaf(w2g[jj][j], v, d[jj]);
    }
    red_level7<0x124>(s, sq, d);
    red_level7<0x128>(s, sq, d);
    red_level7<0x39>(s, sq, d);
    red_level7<0x4E>(s, sq, d);
    float mean = s * (1.f / 128.f);
    float var  = sq * (1.f / 128.f) - mean * mean;
    float rstd = rsqrtf(var + EPSL);
    float p[5];
#pragma unroll
    for (int jj = 0; jj < 5; jj++)
      p[jj] = rstd * (d[jj] - mean * Gs[jj]) + Bs[jj];
    float psel = (l15 == 0) ? p[0] : (l15 == 1) ? p[1] :
                 (l15 == 2) ? p[2] : (l15 == 3) ? p[3] : p[4];
    if (l15 < 5) p_lds[wave][q][l15] = psel;
    asm volatile("s_waitcnt lgkmcnt(0)" ::: "memory");   // wave-local handoff
    const int idx = (l15 < 5) ? l15 : 0;
#pragma unroll
    for (int g = 0; g < 4; g++) {        // 4 serial RNN2 steps (all groups
      float pv = p_lds[wave][g][idx];    //  replicate the same chain)
      float a = pv + t2_l;
#pragma unroll
      for (int jj = 0; jj < 5; jj++) a = fmaf(wrow[jj], h2rep[jj], a);
      float xn = tanh_fast(a);
      float s2 = dpp_sum16(xn * validf) * 0.2f;
      float dd = xn - s2;
      float v2 = dpp_sum16(dd * dd * validf) * 0.2f;
      float r2 = rsqrtf(v2 + EPSL);
      pool_l += dd * r2 * g2_l + be2_l;
      h2rep[0] = bcast16<0>(xn); h2rep[1] = bcast16<1>(xn);
      h2rep[2] = bcast16<2>(xn); h2rep[3] = bcast16<3>(xn);
      h2rep[4] = bcast16<4>(xn);
    }
  }

  float lg = pool_l * (1.f / 256.f);
  float mx = dpp_max16((l15 < 5) ? lg : -3.0e38f);
  float e  = (l15 < 5) ? __expf(lg - mx) : 0.f;
  float sm = dpp_sum16(e);
  if (q == 0 && l15 < 5) out[(size_t)b * 5 + l15] = e / sm;
}

// ===================== Fallback: R9 fused single kernel =====================
__global__ __launch_bounds__(512, 2)
void rnn_fused_fb(const int* __restrict__ x, const float* __restrict__ emb,
                  const float* __restrict__ Wih1, const float* __restrict__ bih1,
                  const float* __restrict__ Whh1, const float* __restrict__ bhh1,
                  const float* __restrict__ g1, const float* __restrict__ be1,
                  const float* __restrict__ Wih2, const float* __restrict__ bih2,
                  const float* __restrict__ Whh2, const float* __restrict__ bhh2,
                  const float* __restrict__ g2, const float* __restrict__ be2,
                  float* __restrict__ out)
{
  __shared__ __align__(16) unsigned short h_bf[2][16 * 128];
  __shared__ __align__(16) unsigned short e_bf[2][16 * 128];
  __shared__ int x_tile[16 * 256];

  const int tid  = threadIdx.x;
  const int wave = tid >> 6;
  const int lane = tid & 63;
  const int r0   = blockIdx.x * 16;
  const int l15  = lane & 15;
  const int q    = lane >> 4;

  for (int i = tid; i < 16 * 256; i += 512)
    x_tile[i] = x[(size_t)(r0 + (i >> 8)) * S_LEN + (i & 255)];
  for (int i = tid; i < 16 * 128; i += 512) h_bf[1][i] = 0;

  const int n1 = wave * 16 + l15;
  const float bias1v = bih1[n1] + bhh1[n1];
  bf16x8 wh[4], wih[4];
#pragma unroll
  for (int kt = 0; kt < 4; kt++) {
    int k0 = kt * 32 + q * 8;
    Frag8 fh, fa;
#pragma unroll
    for (int j = 0; j < 8; j++) {
      fh.us[j] = f2bf_bits(Whh1[n1 * DIM + k0 + j]);
      fa.us[j] = f2bf_bits(Wih1[n1 * DIM + k0 + j]);
    }
    wh[kt] = fh.v; wih[kt] = fa.v;
  }

  const bool ln_role = (wave < 4);
  float w2g[5][8], Gs[5], Bs[5], wrow[5];
  float t2_l = 0.f, g2_l = 0.f, be2_l = 0.f, validf = 0.f;
  float h2rep[5], pool_l = 0.f;
  int myrow = 0;
  float pf[2][8];
  const int gm   = (wave & 3) * 4 + q;
  const int goct = l15;
  const int gdst = gm * 128 + ((goct ^ gm) & 15) * 8;

  if (ln_role) {
    myrow = wave * 4 + q;
    int coct = (l15 ^ myrow) & 15;
#pragma unroll
    for (int j = 0; j < 8; j++) {
      int c = coct * 8 + j;
      float gc = g1[c];
#pragma unroll
      for (int jj = 0; jj < 5; jj++) w2g[jj][j] = Wih2[jj * DIM + c] * gc;
    }
#pragma unroll
    for (int jj = 0; jj < 5; jj++) { Gs[jj] = 0.f; Bs[jj] = 0.f; }
    for (int c = 0; c < DIM; c++) {
      float gc = g1[c], bc = be1[c];
#pragma unroll
      for (int jj = 0; jj < 5; jj++) {
        float w = Wih2[jj * DIM + c];
        Gs[jj] += w * gc; Bs[jj] += w * bc;
      }
    }
    validf = (l15 < 5) ? 1.f : 0.f;
    if (l15 < 5) {
      t2_l = bih2[l15] + bhh2[l15];
      g2_l = g2[l15]; be2_l = be2[l15];
#pragma unroll
      for (int jj = 0; jj < 5; jj++) wrow[jj] = Whh2[l15 * 5 + jj];
    } else {
#pragma unroll
      for (int jj = 0; jj < 5; jj++) wrow[jj] = 0.f;
    }
#pragma unroll
    for (int jj = 0; jj < 5; jj++) h2rep[jj] = 0.f;
  }
  __syncthreads();

  if (!ln_role) {
    float ta[8], tb[8];
    { int xid = x_tile[gm * 256 + 0];
      const float* pe = emb + (size_t)xid * DIM + goct * 8;
#pragma unroll
      for (int j = 0; j < 8; j++) ta[j] = pe[j]; }
    { int xid = x_tile[gm * 256 + 1];
      const float* pe = emb + (size_t)xid * DIM + goct * 8;
#pragma unroll
      for (int j = 0; j < 8; j++) tb[j] = pe[j]; }
    { int xid = x_tile[gm * 256 + 2];
      const float* pe = emb + (size_t)xid * DIM + goct * 8;
#pragma unroll
      for (int j = 0; j < 8; j++) pf[0][j] = pe[j]; }
    { int xid = x_tile[gm * 256 + 3];
      const float* pe = emb + (size_t)xid * DIM + goct * 8;
#pragma unroll
      for (int j = 0; j < 8; j++) pf[1][j] = pe[j]; }
    Frag8 pa, pb;
#pragma unroll
    for (int j = 0; j < 8; j++) { pa.us[j] = f2bf_bits(ta[j]); pb.us[j] = f2bf_bits(tb[j]); }
    *(int4*)&e_bf[0][gdst] = pa.i4;
    *(int4*)&e_bf[1][gdst] = pb.i4;
  }
  __syncthreads();

  f32x4 xpacc = {bias1v, bias1v, bias1v, bias1v};
#pragma unroll
  for (int kt = 0; kt < 4; kt++) {
    int sw = (((kt * 4 + q) ^ l15) & 15) * 8;
    bf16x8 ae = *(const bf16x8*)&e_bf[0][l15 * 128 + sw];
    xpacc = __builtin_amdgcn_mfma_f32_16x16x32_bf16(ae, wih[kt], xpacc, 0, 0, 0);
  }
  asm volatile("s_waitcnt lgkmcnt(0)\n\ts_barrier" ::: "memory");

#pragma unroll 2
  for (int t = 0; t <= S_LEN; t++) {
    f32x4 acc = xpacc;
    if (t < S_LEN) {
      const int rb = (t + 1) & 1;
#pragma unroll
      for (int kt = 0; kt < 4; kt++) {
        int sw = (((kt * 4 + q) ^ l15) & 15) * 8;
        bf16x8 ahf = *(const bf16x8*)&h_bf[rb][l15 * 128 + sw];
        acc = __builtin_amdgcn_mfma_f32_16x16x32_bf16(ahf, wh[kt], acc, 0, 0, 0);
      }
      const int wb = t & 1;
      const int oct = n1 >> 3;
#pragma unroll
      for (int r = 0; r < 4; r++) {
        int row = q * 4 + r;
        h_bf[wb][row * 128 + ((oct ^ row) & 15) * 8 + (n1 & 7)] =
            (unsigned short)f2bf_rhu(tanh_fast(acc[r]));
      }
    }
    if (t + 1 < S_LEN) {
      f32x4 a = {bias1v, bias1v, bias1v, bias1v};
#pragma unroll
      for (int kt = 0; kt < 4; kt++) {
        int sw = (((kt * 4 + q) ^ l15) & 15) * 8;
        bf16x8 ae = *(const bf16x8*)&e_bf[(t + 1) & 1][l15 * 128 + sw];
        a = __builtin_amdgcn_mfma_f32_16x16x32_bf16(ae, wih[kt], a, 0, 0, 0);
      }
      xpacc = a;
    }
    if (!ln_role) {
      if (t + 2 < S_LEN) {
        int4 pk;
        pk.x = pack_rhu(pf[t & 1][0], pf[t & 1][1]);
        pk.y = pack_rhu(pf[t & 1][2], pf[t & 1][3]);
        pk.z = pack_rhu(pf[t & 1][4], pf[t & 1][5]);
        pk.w = pack_rhu(pf[t & 1][6], pf[t & 1][7]);
        *(int4*)&e_bf[t & 1][gdst] = pk;
      }
      if (t + 4 < S_LEN) {
        int xid = x_tile[gm * 256 + t + 4];
        const float* pe = emb + (size_t)xid * DIM + goct * 8;
#pragma unroll
        for (int j = 0; j < 8; j++) pf[t & 1][j] = pe[j];
      }
    } else if (t >= 1) {
      const int hb = (t - 1) & 1;
      Frag8 hr;
      hr.i4 = *(const int4*)&h_bf[hb][myrow * 128 + l15 * 8];
      float s = 0.f, sq = 0.f, d[5] = {0, 0, 0, 0, 0};
#pragma unroll
      for (int j = 0; j < 8; j++) {
        float v = bf2f_bits(hr.us[j]);
        s += v; sq += v * v;
#pragma unroll
        for (int jj = 0; jj < 5; jj++) d[jj] = fmaf(w2g[jj][j], v, d[jj]);
      }
      red_level7<0x124>(s, sq, d);
      red_level7<0x128>(s, sq, d);
      red_level7<0x39>(s, sq, d);
      red_level7<0x4E>(s, sq, d);
      float mean = s * (1.f / 128.f);
      float var  = sq * (1.f / 128.f) - mean * mean;
      float rstd = rsqrtf(var + EPSL);
      float p[5];
#pragma unroll
      for (int jj = 0; jj < 5; jj++)
        p[jj] = rstd * (d[jj] - mean * Gs[jj]) + Bs[jj];
      float psel = (l15 == 0) ? p[0] : (l15 == 1) ? p[1] :
                   (l15 == 2) ? p[2] : (l15 == 3) ? p[3] : p[4];
      float a = psel + t2_l;
#pragma unroll
      for (int jj = 0; jj < 5; jj++) a = fmaf(wrow[jj], h2rep[jj], a);
      float xn = tanh_fast(a);
      float s2 = dpp_sum16(xn * validf) * 0.2f;
      float dd = xn - s2;
      float v2 = dpp_sum16(dd * dd * validf) * 0.2f;
      float r2 = rsqrtf(v2 + EPSL);
      pool_l += dd * r2 * g2_l + be2_l;
      h2rep[0] = bcast16<0>(xn); h2rep[1] = bcast16<1>(xn);
      h2rep[2] = bcast16<2>(xn); h2rep[3] = bcast16<3>(xn);
      h2rep[4] = bcast16<4>(xn);
    }
    asm volatile("s_waitcnt lgkmcnt(0)\n\ts_barrier" ::: "memory");
  }

  if (ln_role) {
    float lg = pool_l * (1.f / 256.f);
    float mx = dpp_max16((l15 < 5) ? lg : -3.0e38f);
    float e  = (l15 < 5) ? __expf(lg - mx) : 0.f;
    float sm = dpp_sum16(e);
    if (l15 < 5) out[(size_t)(r0 + myrow) * 5 + l15] = e / sm;
  }
}

extern "C" void kernel_launch(void* const* d_in, const int* in_sizes, int n_in,
                              void* d_out, int out_size, void* d_ws, size_t ws_size,
                              hipStream_t stream) {
  (void)in_sizes; (void)n_in; (void)out_size;
  const int*   x    = (const int*)  d_in[0];
  const float* emb  = (const float*)d_in[1];
  const float* Wih1 = (const float*)d_in[2];
  const float* bih1 = (const float*)d_in[3];
  const float* Whh1 = (const float*)d_in[4];
  const float* bhh1 = (const float*)d_in[5];
  const float* g1   = (const float*)d_in[6];
  const float* be1  = (const float*)d_in[7];
  const float* Wih2 = (const float*)d_in[8];
  const float* bih2 = (const float*)d_in[9];
  const float* Whh2 = (const float*)d_in[10];
  const float* bhh2 = (const float*)d_in[11];
  const float* g2   = (const float*)d_in[12];
  const float* be2  = (const float*)d_in[13];
  float* out = (float*)d_out;

  const size_t HBYTES = (size_t)1024 * S_LEN * DIM * 2;   // 64 MiB bf16 h-buffer
  if (ws_size >= HBYTES) {
    unsigned short* hws = (unsigned short*)d_ws;
    rnn_core<<<dim3(64), dim3(512), 0, stream>>>(x, emb, Wih1, bih1, Whh1, bhh1, hws);
    rnn_tail<<<dim3(256), dim3(256), 0, stream>>>(hws, g1, be1, Wih2, bih2,
                                                  Whh2, bhh2, g2, be2, out);
  } else {
    rnn_fused_fb<<<dim3(64), dim3(512), 0, stream>>>(
        x, emb, Wih1, bih1, Whh1, bhh1, g1, be1,
        Wih2, bih2, Whh2, bhh2, g2, be2, out);
  }
}